// Round 10
// baseline (288.240 us; speedup 1.0000x reference)
//
#include <hip/hip_runtime.h>

// MFMA fragment types (f16)
typedef _Float16 f16x8 __attribute__((ext_vector_type(8)));
typedef __fp16   fp16x2 __attribute__((ext_vector_type(2)));
typedef float f32x16 __attribute__((ext_vector_type(16)));

__device__ __forceinline__ unsigned pkrtz(float a, float b) {
    fp16x2 h = __builtin_amdgcn_cvt_pkrtz(a, b);   // src0->low, src1->high
    union { fp16x2 h; unsigned u; } c; c.h = h; return c.u;
}

__device__ __forceinline__ unsigned short f2h(float f) {
    _Float16 h = (_Float16)f;
    union { _Float16 h; unsigned short s; } c; c.h = h; return c.s;
}

__device__ __forceinline__ f16x8 pack8(const float* v) {
    union { unsigned u[4]; f16x8 h; } c;
    c.u[0] = pkrtz(v[0], v[1]);
    c.u[1] = pkrtz(v[2], v[3]);
    c.u[2] = pkrtz(v[4], v[5]);
    c.u[3] = pkrtz(v[6], v[7]);
    return c.h;
}

// ---------------------------------------------------------------------------
// prep v2 (MFMA GEMM, r8-proven: -7us total). 4 waves x one 32x32 tile each
// for BOTH Q and V; acc written through LDS (reusing weight buffers), then
// the r0-proven coalesced epilogue.
// ---------------------------------------------------------------------------
__global__ __launch_bounds__(256) void prep_kernel(
    const float* __restrict__ src,
    const float* __restrict__ wq, const float* __restrict__ bq,
    const float* __restrict__ wv, const float* __restrict__ bv,
    unsigned short* __restrict__ Qg, unsigned short* __restrict__ Vtg)
{
    __shared__ float slab[64][65];
    __shared__ float wqs[4160];   // weights [k*64+j]; reused as outQ[c*65+j]
    __shared__ float wvs[4160];   // weights [k*64+j]; reused as outV[c*65+j]

    const int t  = threadIdx.x;
    const int bx = blockIdx.x, b = blockIdx.y;
    const int lane = t & 63, w = t >> 6;
    const int l32 = lane & 31, hi = lane >> 5;

    {   // stage weights (linear [k*64+j])
        const float4* wq4 = (const float4*)wq;
        const float4* wv4 = (const float4*)wv;
        float4* q4 = (float4*)wqs; float4* v4 = (float4*)wvs;
        #pragma unroll
        for (int i = 0; i < 4; ++i) {
            q4[i*256 + t] = wq4[i*256 + t];
            v4[i*256 + t] = wv4[i*256 + t];
        }
    }
    {   // stage slab: k=h rows (stride 4096), bx=w fixed
        const int k = t >> 2, c0 = (t & 3) << 4;
        const size_t sb = (size_t)b*262144 + (size_t)k*4096 + (size_t)bx*64 + c0;
        #pragma unroll
        for (int i = 0; i < 4; ++i)
            *(float4*)&slab[k][c0 + i*4] = *(const float4*)&src[sb + i*4];
    }
    __syncthreads();

    const int mt = w >> 1, nt = w & 1;   // wave's 32x32 tile
    f16x8 xa[4], wqb[4], wvb[4];
    #pragma unroll
    for (int s = 0; s < 4; ++s) {
        const int k0 = s*16 + hi*8;
        float av[8], qv[8], vv[8];
        #pragma unroll
        for (int jj = 0; jj < 8; ++jj) {
            av[jj] = slab[k0 + jj][mt*32 + l32];
            qv[jj] = wqs[(k0 + jj)*64 + nt*32 + l32];
            vv[jj] = wvs[(k0 + jj)*64 + nt*32 + l32];
        }
        xa[s]  = pack8(av);
        wqb[s] = pack8(qv);
        wvb[s] = pack8(vv);
    }

    f32x16 fz;
    #pragma unroll
    for (int i = 0; i < 16; ++i) fz[i] = 0.f;
    f32x16 accQ = __builtin_amdgcn_mfma_f32_32x32x16_f16(xa[0], wqb[0], fz, 0,0,0);
    f32x16 accV = __builtin_amdgcn_mfma_f32_32x32x16_f16(xa[0], wvb[0], fz, 0,0,0);
    #pragma unroll
    for (int s = 1; s < 4; ++s) {
        accQ = __builtin_amdgcn_mfma_f32_32x32x16_f16(xa[s], wqb[s], accQ, 0,0,0);
        accV = __builtin_amdgcn_mfma_f32_32x32x16_f16(xa[s], wvb[s], accV, 0,0,0);
    }

    __syncthreads();   // all frag reads done -> safe to overwrite weight LDS

    {
        #pragma unroll
        for (int r = 0; r < 16; ++r) {
            const int crow = mt*32 + (r&3) + 8*(r>>2) + 4*hi;
            wqs[crow*65 + nt*32 + l32] = accQ[r];
            wvs[crow*65 + nt*32 + l32] = accV[r];
        }
    }
    __syncthreads();

    const int c = t & 63, jg = t >> 6;
    float qa[16], va[16];
    #pragma unroll
    for (int jj = 0; jj < 16; ++jj) {
        qa[jj] = bq[jg*16+jj] + wqs[c*65 + jg*16 + jj];
        va[jj] = bv[jg*16+jj] + wvs[c*65 + jg*16 + jj];
    }
    const int token = bx*64 + c;
    union { unsigned u[8]; uint4 v[2]; } qp;
    #pragma unroll
    for (int jj = 0; jj < 8; ++jj) qp.u[jj] = pkrtz(qa[2*jj], qa[2*jj+1]);
    const size_t qoff = ((size_t)b*4096 + token)*64 + jg*16;
    *(uint4*)&Qg[qoff]     = qp.v[0];
    *(uint4*)&Qg[qoff + 8] = qp.v[1];
    #pragma unroll
    for (int jj = 0; jj < 16; ++jj)
        Vtg[((size_t)b*64 + jg*16 + jj)*4096 + token] = f2h(va[jj]);
}

// ---------------------------------------------------------------------------
// prep_w v2 (same MFMA GEMM) FUSED with fold_h (r8-proven).
// ---------------------------------------------------------------------------
__global__ __launch_bounds__(256) void prep_w_kernel(
    const float* __restrict__ feature, const float* __restrict__ Pin,
    const float* __restrict__ gate,
    const float* __restrict__ wq, const float* __restrict__ bq,
    const float* __restrict__ wv, const float* __restrict__ bv,
    unsigned short* __restrict__ Qg, unsigned short* __restrict__ Vtg,
    float* __restrict__ x1out, int nsplit)
{
    __shared__ float slab[64][65];
    __shared__ float wqs[4160];
    __shared__ float wvs[4160];

    const int t  = threadIdx.x;
    const int bx = blockIdx.x, b = blockIdx.y;   // bx = h
    const int lane = t & 63, w = t >> 6;
    const int l32 = lane & 31, hi = lane >> 5;

    {   // stage weights
        const float4* wq4 = (const float4*)wq;
        const float4* wv4 = (const float4*)wv;
        float4* q4 = (float4*)wqs; float4* v4 = (float4*)wvs;
        #pragma unroll
        for (int i = 0; i < 4; ++i) {
            q4[i*256 + t] = wq4[i*256 + t];
            v4[i*256 + t] = wv4[i*256 + t];
        }
    }
    {   // stage slab with inline fold: P_h[ks][b][d=h][token=w*64+c]
        const int k = t >> 2, c0 = (t & 3) << 4;
        const size_t off = (size_t)bx*4096 + (size_t)k*64 + c0;  // h*4096 + w*64 + c
        const size_t fb  = (size_t)b*262144 + off;
        const float g = gate[0];
        #pragma unroll
        for (int i = 0; i < 4; ++i) {
            float4 v  = *(const float4*)&feature[fb + i*4];
            float sx = 0.f, sy = 0.f, sz = 0.f, sw = 0.f;
            for (int ks = 0; ks < nsplit; ++ks) {
                float4 pk = *(const float4*)&Pin[((size_t)(ks*4 + b) << 18) + off + i*4];
                sx += pk.x; sy += pk.y; sz += pk.z; sw += pk.w;
            }
            v.x += g * sx; v.y += g * sy; v.z += g * sz; v.w += g * sw;
            *(float4*)&slab[k][c0 + i*4] = v;
            *(float4*)&x1out[fb + i*4] = v;
        }
    }
    __syncthreads();

    const int mt = w >> 1, nt = w & 1;
    f16x8 xa[4], wqb[4], wvb[4];
    #pragma unroll
    for (int s = 0; s < 4; ++s) {
        const int k0 = s*16 + hi*8;
        float av[8], qv[8], vv[8];
        #pragma unroll
        for (int jj = 0; jj < 8; ++jj) {
            av[jj] = slab[k0 + jj][mt*32 + l32];
            qv[jj] = wqs[(k0 + jj)*64 + nt*32 + l32];
            vv[jj] = wvs[(k0 + jj)*64 + nt*32 + l32];
        }
        xa[s]  = pack8(av);
        wqb[s] = pack8(qv);
        wvb[s] = pack8(vv);
    }

    f32x16 fz;
    #pragma unroll
    for (int i = 0; i < 16; ++i) fz[i] = 0.f;
    f32x16 accQ = __builtin_amdgcn_mfma_f32_32x32x16_f16(xa[0], wqb[0], fz, 0,0,0);
    f32x16 accV = __builtin_amdgcn_mfma_f32_32x32x16_f16(xa[0], wvb[0], fz, 0,0,0);
    #pragma unroll
    for (int s = 1; s < 4; ++s) {
        accQ = __builtin_amdgcn_mfma_f32_32x32x16_f16(xa[s], wqb[s], accQ, 0,0,0);
        accV = __builtin_amdgcn_mfma_f32_32x32x16_f16(xa[s], wvb[s], accV, 0,0,0);
    }

    __syncthreads();

    {
        #pragma unroll
        for (int r = 0; r < 16; ++r) {
            const int crow = mt*32 + (r&3) + 8*(r>>2) + 4*hi;
            wqs[crow*65 + nt*32 + l32] = accQ[r];
            wvs[crow*65 + nt*32 + l32] = accV[r];
        }
    }
    __syncthreads();

    const int c = t & 63, jg = t >> 6;
    float qa[16], va[16];
    #pragma unroll
    for (int jj = 0; jj < 16; ++jj) {
        qa[jj] = bq[jg*16+jj] + wqs[c*65 + jg*16 + jj];
        va[jj] = bv[jg*16+jj] + wvs[c*65 + jg*16 + jj];
    }
    const int token = bx*64 + c;
    union { unsigned u[8]; uint4 v[2]; } qp;
    #pragma unroll
    for (int jj = 0; jj < 8; ++jj) qp.u[jj] = pkrtz(qa[2*jj], qa[2*jj+1]);
    const size_t qoff = ((size_t)b*4096 + token)*64 + jg*16;
    *(uint4*)&Qg[qoff]     = qp.v[0];
    *(uint4*)&Qg[qoff + 8] = qp.v[1];
    #pragma unroll
    for (int jj = 0; jj < 16; ++jj)
        Vtg[((size_t)b*64 + jg*16 + jj)*4096 + token] = f2h(va[jj]);
}

// ---------------------------------------------------------------------------
// attn v20: **ZERO LDS, ZERO BARRIERS**. Every fragment loaded directly from
// global (L2-resident per r6's swizzle+FETCH=5.2MB; L1-cacheable 8KB tiles).
// Rationale (r0-r8 ledger): all pipes <15% busy (derived counters inflated
// ~3.6x; real MfmaUtil ~3.7%, VALUBusy ~14%), wall = 7000 cyc/iter vs ~500
// issue floor, insensitive to occupancy/LDS/trans/L2/work-per-slot. The only
// untested structure: LDS round-trip + vmcnt(0)+barrier lockstep that (a)
// couples all 4 waves to the slowest, (b) blocks cross-tile code motion.
// Removing both lets waves drift and the compiler pipeline tile k+1 loads
// under tile k compute.
// K A-frag: lane(l32,hi) = 16B at Qbase+(key+l32)*64+s*16+hi*8 (= old Ksh).
// V B-frag: nu perm folded into addr: pieces at ks*16+hi*4 and ks*16+8+hi*4
// of rows l32 / 32+l32 (= old Vts slots). Epilogue unchanged.
// ---------------------------------------------------------------------------
__global__ __launch_bounds__(256) void attn_kernel(
    const unsigned short* __restrict__ Qg,
    const unsigned short* __restrict__ Vtg,
    float* __restrict__ P)
{
    const int t = threadIdx.x;
    // ---- XCD-aware decode (r6-proven): flat dispatch ID -> (mb,b,ksplit)
    const int flat = blockIdx.x + 32*(blockIdx.y + 4*blockIdx.z);
    const int xcd  = flat & 7;
    const int slot = flat >> 3;                  // 0..63 per XCD
    const int mb   = slot & 31;
    const int grp  = xcd + ((slot >> 5) << 3);   // 0..15, 2 groups per XCD
    const int b      = grp >> 2;
    const int ksplit = grp & 3;
    const int niter = 16;                        // 64 / nsp, nsp = 4
    const int keybase = ksplit * 1024;
    const int lane = t & 63, w = t >> 6;
    const int l32 = lane & 31, hi = lane >> 5;

    const unsigned short* Qbase = Qg  + (size_t)b*262144;
    const unsigned short* Vbase = Vtg + (size_t)b*262144;

    // Q B-frags (n=query=l32, k=d=s*16+hi*8+j), scaled by -0.125*log2(e)
    f16x8 qb[4];
    {
        const unsigned short* qrow = Qbase + (size_t)(mb*128 + w*32 + l32)*64 + hi*8;
        const _Float16 sc = (_Float16)(-0.180336880f);
        #pragma unroll
        for (int s = 0; s < 4; ++s) {
            f16x8 q = *(const f16x8*)(qrow + s*16);
            qb[s] = q * sc;
        }
    }

    f32x16 fz;
    #pragma unroll
    for (int i = 0; i < 16; ++i) fz[i] = 0.f;

    f32x16 y[2];
    y[0] = fz; y[1] = fz;

    // per-lane streaming pointers (advance per key-tile)
    const unsigned short* Krow0 = Qbase + (size_t)(keybase + l32)*64 + hi*8;
    const unsigned short* Krow1 = Qbase + (size_t)(keybase + 32 + l32)*64 + hi*8;
    const unsigned short* Vrow0 = Vbase + (size_t)l32*4096 + keybase + hi*4;
    const unsigned short* Vrow1 = Vbase + (size_t)(32 + l32)*4096 + keybase + hi*4;

    for (int kb = 0; kb < niter; ++kb) {
        // K A-frags: 8x 16B direct loads (rows l32 / 32+l32 of this tile)
        f16x8 ka0[4], ka1[4];
        #pragma unroll
        for (int s = 0; s < 4; ++s) {
            ka0[s] = *(const f16x8*)(Krow0 + s*16);
            ka1[s] = *(const f16x8*)(Krow1 + s*16);
        }
        // V B-frags: 16x 8B direct loads, nu permutation in the addressing.
        // Issued before the QK MFMAs so their latency hides under QK+sigmoid.
        union { uint2 p[2]; f16x8 v; } vb0[4], vb1[4];
        #pragma unroll
        for (int ks = 0; ks < 4; ++ks) {
            vb0[ks].p[0] = *(const uint2*)(Vrow0 + ks*16);
            vb0[ks].p[1] = *(const uint2*)(Vrow0 + ks*16 + 8);
            vb1[ks].p[0] = *(const uint2*)(Vrow1 + ks*16);
            vb1[ks].p[1] = *(const uint2*)(Vrow1 + ks*16 + 8);
        }

        // T = K·Qs^T : tt[u] covers keys u*32..+32 (scale pre-folded)
        f32x16 tt[2];
        #pragma unroll
        for (int s = 0; s < 4; ++s) {
            if (s == 0) {
                tt[0] = __builtin_amdgcn_mfma_f32_32x32x16_f16(ka0[0], qb[0], fz, 0,0,0);
                tt[1] = __builtin_amdgcn_mfma_f32_32x32x16_f16(ka1[0], qb[0], fz, 0,0,0);
            } else {
                tt[0] = __builtin_amdgcn_mfma_f32_32x32x16_f16(ka0[s], qb[s], tt[0], 0,0,0);
                tt[1] = __builtin_amdgcn_mfma_f32_32x32x16_f16(ka1[s], qb[s], tt[1], 0,0,0);
            }
        }

        // sigmoid (pairwise rcp, t clamped) -> pack -> DIRECT A-frag
        #pragma unroll
        for (int u = 0; u < 2; ++u) {
            unsigned pk_[8];
            #pragma unroll
            for (int pr = 0; pr < 8; ++pr) {
                float t0 = __builtin_fminf(tt[u][2*pr+0], 60.0f);
                float t1 = __builtin_fminf(tt[u][2*pr+1], 60.0f);
                float e0 = __builtin_exp2f(t0);
                float e1 = __builtin_exp2f(t1);
                float d0 = 1.0f + e0, d1 = 1.0f + e1;
                float rr = __builtin_amdgcn_rcpf(d0 * d1);
                pk_[pr] = pkrtz(rr * d1, rr * d0);
            }
            #pragma unroll
            for (int sp = 0; sp < 2; ++sp) {
                union { unsigned u4[4]; f16x8 v; } sa;
                sa.u4[0] = pk_[sp*4 + 0];
                sa.u4[1] = pk_[sp*4 + 1];
                sa.u4[2] = pk_[sp*4 + 2];
                sa.u4[3] = pk_[sp*4 + 3];
                const int ks = u*2 + sp;
                y[0] = __builtin_amdgcn_mfma_f32_32x32x16_f16(sa.v, vb0[ks].v, y[0], 0,0,0);
                y[1] = __builtin_amdgcn_mfma_f32_32x32x16_f16(sa.v, vb1[ks].v, y[1], 0,0,0);
            }
        }

        Krow0 += 64*64; Krow1 += 64*64;   // next 64 keys (row stride 64 halves)
        Vrow0 += 64;    Vrow1 += 64;      // next 64 keys (col offset)
    }

    // epilogue: P[ksplit][b][d][token]; token = mb*128 + w*32 + 8g + 4hi + e
    float* Pp = P + (((size_t)(ksplit*4 + b)) << 18);
    const int token0 = mb*128 + w*32 + hi*4;
    #pragma unroll
    for (int dt = 0; dt < 2; ++dt) {
        const int d = dt*32 + l32;
        #pragma unroll
        for (int g = 0; g < 4; ++g) {
            float4 v;
            v.x = y[dt][4*g+0]; v.y = y[dt][4*g+1];
            v.z = y[dt][4*g+2]; v.w = y[dt][4*g+3];
            *(float4*)&Pp[(size_t)d*4096 + token0 + 8*g] = v;
        }
    }
}

// ---------------------------------------------------------------------------
// final: out = p * (feature + x1 + g*sum_ks P_w[ks][b][d=w][token=h*64+c])
// ---------------------------------------------------------------------------
__global__ __launch_bounds__(256) void final_kernel(
    const float* __restrict__ feature, const float* __restrict__ x1,
    const float* __restrict__ Pin, const float* __restrict__ predict,
    const float* __restrict__ conv_w, const float* __restrict__ conv_b,
    const float* __restrict__ gate, float* __restrict__ out, int nsplit)
{
    const int i4 = blockIdx.x * 256 + threadIdx.x;   // [0, 262144)
    const int j = i4 << 2;
    const int pix = j >> 6;
    const float* row = predict + (size_t)pix * 19;
    float pv = conv_b[0];
    #pragma unroll
    for (int i = 0; i < 19; ++i) {
        float sg = __builtin_amdgcn_rcpf(1.0f + __builtin_exp2f(-1.442695041f * row[i]));
        pv += (1.0f - sg) * conv_w[i];
    }

    const int b = j >> 18, h = (j >> 12) & 63, d = (j >> 6) & 63, c = j & 63;
    const size_t pif = ((size_t)(b*64 + d) << 12) + h*64 + c;
    float sx = 0.f, sy = 0.f, sz = 0.f, sw = 0.f;
    for (int ks = 0; ks < nsplit; ++ks) {
        float4 pk = *(const float4*)&Pin[((size_t)ks << 20) + pif];
        sx += pk.x; sy += pk.y; sz += pk.z; sw += pk.w;
    }
    const float g = gate[0];
    float4 f = ((const float4*)feature)[i4];
    float4 x = ((const float4*)x1)[i4];
    float4 o;
    o.x = pv * (f.x + x.x + g * sx);
    o.y = pv * (f.y + x.y + g * sy);
    o.z = pv * (f.z + x.z + g * sz);
    o.w = pv * (f.w + x.w + g * sw);
    ((float4*)out)[i4] = o;
}

extern "C" void kernel_launch(void* const* d_in, const int* in_sizes, int n_in,
                              void* d_out, int out_size, void* d_ws, size_t ws_size,
                              hipStream_t stream) {
    const float* feature = (const float*)d_in[0];
    const float* predict = (const float*)d_in[1];
    const float* hq_w = (const float*)d_in[2];
    const float* hq_b = (const float*)d_in[3];
    const float* hv_w = (const float*)d_in[4];
    const float* hv_b = (const float*)d_in[5];
    const float* wq_w = (const float*)d_in[6];
    const float* wq_b = (const float*)d_in[7];
    const float* wv_w = (const float*)d_in[8];
    const float* wv_b = (const float*)d_in[9];
    const float* h_gate = (const float*)d_in[10];
    const float* w_gate = (const float*)d_in[11];
    const float* conv_w = (const float*)d_in[12];
    const float* conv_b = (const float*)d_in[13];
    float* out = (float*)d_out;

    // workspace: Qg 2MB | Vtg 2MB | x1 4MB | P nsplit*4MB (nsplit=4 -> 24 MiB)
    char* ws = (char*)d_ws;
    unsigned short* Qg  = (unsigned short*)(ws);
    unsigned short* Vtg = (unsigned short*)(ws + (2u << 20));
    float*          x1  = (float*)(ws + (4u << 20));
    float*          P   = (float*)(ws + (8u << 20));
    const int nsplit = 4;

    dim3 blk(256);
    // height stage
    prep_kernel<<<dim3(64, 4), blk, 0, stream>>>(feature, hq_w, hq_b, hv_w, hv_b,
                                                 Qg, Vtg);
    attn_kernel<<<dim3(32, 4, 4), blk, 0, stream>>>(Qg, Vtg, P);
    // width stage: x1 = feature + h_gate*sum(P) fused into staging
    prep_w_kernel<<<dim3(64, 4), blk, 0, stream>>>(feature, P, h_gate,
                                                   wq_w, wq_b, wv_w, wv_b,
                                                   Qg, Vtg, x1, nsplit);
    attn_kernel<<<dim3(32, 4, 4), blk, 0, stream>>>(Qg, Vtg, P);
    // out = p * (feature + x1 + w_gate*sum(P))
    final_kernel<<<dim3(1024), blk, 0, stream>>>(feature, x1, P, predict,
                                                 conv_w, conv_b, w_gate, out, nsplit);
}

// Round 11
// 179.859 us; speedup vs baseline: 1.6026x; 1.6026x over previous
//
#include <hip/hip_runtime.h>

// MFMA fragment types (f16)
typedef _Float16 f16x8 __attribute__((ext_vector_type(8)));
typedef __fp16   fp16x2 __attribute__((ext_vector_type(2)));
typedef float f32x16 __attribute__((ext_vector_type(16)));

__device__ __forceinline__ unsigned pkrtz(float a, float b) {
    fp16x2 h = __builtin_amdgcn_cvt_pkrtz(a, b);   // src0->low, src1->high
    union { fp16x2 h; unsigned u; } c; c.h = h; return c.u;
}

__device__ __forceinline__ unsigned short f2h(float f) {
    _Float16 h = (_Float16)f;
    union { _Float16 h; unsigned short s; } c; c.h = h; return c.s;
}

__device__ __forceinline__ f16x8 pack8(const float* v) {
    union { unsigned u[4]; f16x8 h; } c;
    c.u[0] = pkrtz(v[0], v[1]);
    c.u[1] = pkrtz(v[2], v[3]);
    c.u[2] = pkrtz(v[4], v[5]);
    c.u[3] = pkrtz(v[6], v[7]);
    return c.h;
}

// ---------------------------------------------------------------------------
// prep v2 (MFMA GEMM, r8-proven: -7us total vs scalar-FMA prep). 4 waves x
// one 32x32 tile each for BOTH Q and V; acc written through LDS (reusing
// weight buffers), then the r0-proven coalesced epilogue.
// ---------------------------------------------------------------------------
__global__ __launch_bounds__(256) void prep_kernel(
    const float* __restrict__ src,
    const float* __restrict__ wq, const float* __restrict__ bq,
    const float* __restrict__ wv, const float* __restrict__ bv,
    unsigned short* __restrict__ Qg, unsigned short* __restrict__ Vtg)
{
    __shared__ float slab[64][65];
    __shared__ float wqs[4160];   // weights [k*64+j]; reused as outQ[c*65+j]
    __shared__ float wvs[4160];   // weights [k*64+j]; reused as outV[c*65+j]

    const int t  = threadIdx.x;
    const int bx = blockIdx.x, b = blockIdx.y;
    const int lane = t & 63, w = t >> 6;
    const int l32 = lane & 31, hi = lane >> 5;

    {   // stage weights (linear [k*64+j])
        const float4* wq4 = (const float4*)wq;
        const float4* wv4 = (const float4*)wv;
        float4* q4 = (float4*)wqs; float4* v4 = (float4*)wvs;
        #pragma unroll
        for (int i = 0; i < 4; ++i) {
            q4[i*256 + t] = wq4[i*256 + t];
            v4[i*256 + t] = wv4[i*256 + t];
        }
    }
    {   // stage slab: k=h rows (stride 4096), bx=w fixed
        const int k = t >> 2, c0 = (t & 3) << 4;
        const size_t sb = (size_t)b*262144 + (size_t)k*4096 + (size_t)bx*64 + c0;
        #pragma unroll
        for (int i = 0; i < 4; ++i)
            *(float4*)&slab[k][c0 + i*4] = *(const float4*)&src[sb + i*4];
    }
    __syncthreads();

    const int mt = w >> 1, nt = w & 1;   // wave's 32x32 tile
    f16x8 xa[4], wqb[4], wvb[4];
    #pragma unroll
    for (int s = 0; s < 4; ++s) {
        const int k0 = s*16 + hi*8;
        float av[8], qv[8], vv[8];
        #pragma unroll
        for (int jj = 0; jj < 8; ++jj) {
            av[jj] = slab[k0 + jj][mt*32 + l32];
            qv[jj] = wqs[(k0 + jj)*64 + nt*32 + l32];
            vv[jj] = wvs[(k0 + jj)*64 + nt*32 + l32];
        }
        xa[s]  = pack8(av);
        wqb[s] = pack8(qv);
        wvb[s] = pack8(vv);
    }

    f32x16 fz;
    #pragma unroll
    for (int i = 0; i < 16; ++i) fz[i] = 0.f;
    f32x16 accQ = __builtin_amdgcn_mfma_f32_32x32x16_f16(xa[0], wqb[0], fz, 0,0,0);
    f32x16 accV = __builtin_amdgcn_mfma_f32_32x32x16_f16(xa[0], wvb[0], fz, 0,0,0);
    #pragma unroll
    for (int s = 1; s < 4; ++s) {
        accQ = __builtin_amdgcn_mfma_f32_32x32x16_f16(xa[s], wqb[s], accQ, 0,0,0);
        accV = __builtin_amdgcn_mfma_f32_32x32x16_f16(xa[s], wvb[s], accV, 0,0,0);
    }

    __syncthreads();   // all frag reads done -> safe to overwrite weight LDS

    {
        #pragma unroll
        for (int r = 0; r < 16; ++r) {
            const int crow = mt*32 + (r&3) + 8*(r>>2) + 4*hi;
            wqs[crow*65 + nt*32 + l32] = accQ[r];
            wvs[crow*65 + nt*32 + l32] = accV[r];
        }
    }
    __syncthreads();

    const int c = t & 63, jg = t >> 6;
    float qa[16], va[16];
    #pragma unroll
    for (int jj = 0; jj < 16; ++jj) {
        qa[jj] = bq[jg*16+jj] + wqs[c*65 + jg*16 + jj];
        va[jj] = bv[jg*16+jj] + wvs[c*65 + jg*16 + jj];
    }
    const int token = bx*64 + c;
    union { unsigned u[8]; uint4 v[2]; } qp;
    #pragma unroll
    for (int jj = 0; jj < 8; ++jj) qp.u[jj] = pkrtz(qa[2*jj], qa[2*jj+1]);
    const size_t qoff = ((size_t)b*4096 + token)*64 + jg*16;
    *(uint4*)&Qg[qoff]     = qp.v[0];
    *(uint4*)&Qg[qoff + 8] = qp.v[1];
    #pragma unroll
    for (int jj = 0; jj < 16; ++jj)
        Vtg[((size_t)b*64 + jg*16 + jj)*4096 + token] = f2h(va[jj]);
}

// ---------------------------------------------------------------------------
// prep_w v2 (same MFMA GEMM) FUSED with fold_h (r8-proven).
// ---------------------------------------------------------------------------
__global__ __launch_bounds__(256) void prep_w_kernel(
    const float* __restrict__ feature, const float* __restrict__ Pin,
    const float* __restrict__ gate,
    const float* __restrict__ wq, const float* __restrict__ bq,
    const float* __restrict__ wv, const float* __restrict__ bv,
    unsigned short* __restrict__ Qg, unsigned short* __restrict__ Vtg,
    float* __restrict__ x1out, int nsplit)
{
    __shared__ float slab[64][65];
    __shared__ float wqs[4160];
    __shared__ float wvs[4160];

    const int t  = threadIdx.x;
    const int bx = blockIdx.x, b = blockIdx.y;   // bx = h
    const int lane = t & 63, w = t >> 6;
    const int l32 = lane & 31, hi = lane >> 5;

    {   // stage weights
        const float4* wq4 = (const float4*)wq;
        const float4* wv4 = (const float4*)wv;
        float4* q4 = (float4*)wqs; float4* v4 = (float4*)wvs;
        #pragma unroll
        for (int i = 0; i < 4; ++i) {
            q4[i*256 + t] = wq4[i*256 + t];
            v4[i*256 + t] = wv4[i*256 + t];
        }
    }
    {   // stage slab with inline fold: P_h[ks][b][d=h][token=w*64+c]
        const int k = t >> 2, c0 = (t & 3) << 4;
        const size_t off = (size_t)bx*4096 + (size_t)k*64 + c0;  // h*4096 + w*64 + c
        const size_t fb  = (size_t)b*262144 + off;
        const float g = gate[0];
        #pragma unroll
        for (int i = 0; i < 4; ++i) {
            float4 v  = *(const float4*)&feature[fb + i*4];
            float sx = 0.f, sy = 0.f, sz = 0.f, sw = 0.f;
            for (int ks = 0; ks < nsplit; ++ks) {
                float4 pk = *(const float4*)&Pin[((size_t)(ks*4 + b) << 18) + off + i*4];
                sx += pk.x; sy += pk.y; sz += pk.z; sw += pk.w;
            }
            v.x += g * sx; v.y += g * sy; v.z += g * sz; v.w += g * sw;
            *(float4*)&slab[k][c0 + i*4] = v;
            *(float4*)&x1out[fb + i*4] = v;
        }
    }
    __syncthreads();

    const int mt = w >> 1, nt = w & 1;
    f16x8 xa[4], wqb[4], wvb[4];
    #pragma unroll
    for (int s = 0; s < 4; ++s) {
        const int k0 = s*16 + hi*8;
        float av[8], qv[8], vv[8];
        #pragma unroll
        for (int jj = 0; jj < 8; ++jj) {
            av[jj] = slab[k0 + jj][mt*32 + l32];
            qv[jj] = wqs[(k0 + jj)*64 + nt*32 + l32];
            vv[jj] = wvs[(k0 + jj)*64 + nt*32 + l32];
        }
        xa[s]  = pack8(av);
        wqb[s] = pack8(qv);
        wvb[s] = pack8(vv);
    }

    f32x16 fz;
    #pragma unroll
    for (int i = 0; i < 16; ++i) fz[i] = 0.f;
    f32x16 accQ = __builtin_amdgcn_mfma_f32_32x32x16_f16(xa[0], wqb[0], fz, 0,0,0);
    f32x16 accV = __builtin_amdgcn_mfma_f32_32x32x16_f16(xa[0], wvb[0], fz, 0,0,0);
    #pragma unroll
    for (int s = 1; s < 4; ++s) {
        accQ = __builtin_amdgcn_mfma_f32_32x32x16_f16(xa[s], wqb[s], accQ, 0,0,0);
        accV = __builtin_amdgcn_mfma_f32_32x32x16_f16(xa[s], wvb[s], accV, 0,0,0);
    }

    __syncthreads();

    {
        #pragma unroll
        for (int r = 0; r < 16; ++r) {
            const int crow = mt*32 + (r&3) + 8*(r>>2) + 4*hi;
            wqs[crow*65 + nt*32 + l32] = accQ[r];
            wvs[crow*65 + nt*32 + l32] = accV[r];
        }
    }
    __syncthreads();

    const int c = t & 63, jg = t >> 6;
    float qa[16], va[16];
    #pragma unroll
    for (int jj = 0; jj < 16; ++jj) {
        qa[jj] = bq[jg*16+jj] + wqs[c*65 + jg*16 + jj];
        va[jj] = bv[jg*16+jj] + wvs[c*65 + jg*16 + jj];
    }
    const int token = bx*64 + c;
    union { unsigned u[8]; uint4 v[2]; } qp;
    #pragma unroll
    for (int jj = 0; jj < 8; ++jj) qp.u[jj] = pkrtz(qa[2*jj], qa[2*jj+1]);
    const size_t qoff = ((size_t)b*4096 + token)*64 + jg*16;
    *(uint4*)&Qg[qoff]     = qp.v[0];
    *(uint4*)&Qg[qoff + 8] = qp.v[1];
    #pragma unroll
    for (int jj = 0; jj < 16; ++jj)
        Vtg[((size_t)b*64 + jg*16 + jj)*4096 + token] = f2h(va[jj]);
}

// ---------------------------------------------------------------------------
// attn v14 — the r0 structure VERBATIM (best measured: 44.7-45.0us across 5
// dispatches; every variant lost: +occupancy null r1, -LDS -6% r2, VALU-
// sigmoid null r3, XCD swizzle +5% r6, 2-query fusion +3% r7, no-LDS 2x r10).
// f16 32x32x16 MFMA; V staged with per-16 key permutation nu so the S-V
// A-frag is exactly C-regs of T=K*Q^T; pairwise-rcp sigmoid (t<=60);
// LDS ping-pong with ONE barrier/iter; register prefetch spans compute.
// ---------------------------------------------------------------------------
__global__ __launch_bounds__(256) void attn_kernel(
    const unsigned short* __restrict__ Qg,
    const unsigned short* __restrict__ Vtg,
    float* __restrict__ P)
{
    __shared__ unsigned short Ksh[2][64][72];
    __shared__ unsigned short Vts[2][64][72];

    const int t = threadIdx.x;
    const int mb = blockIdx.x, b = blockIdx.y, ksplit = blockIdx.z;
    const int nsp = gridDim.z;
    const int niter = 64 / nsp;
    const int keybase = ksplit * (4096 / nsp);
    const int lane = t & 63, w = t >> 6;
    const int l32 = lane & 31, hi = lane >> 5;

    const unsigned short* Qbase = Qg  + (size_t)b*262144;
    const unsigned short* Vbase = Vtg + (size_t)b*262144;

    // Q B-frags (n=query=l32, k=d=s*16+hi*8+j), scaled by -0.125*log2(e)
    f16x8 qb[4];
    {
        const unsigned short* qrow = Qbase + (size_t)(mb*128 + w*32 + l32)*64 + hi*8;
        const _Float16 sc = (_Float16)(-0.180336880f);
        #pragma unroll
        for (int s = 0; s < 4; ++s) {
            f16x8 q = *(const f16x8*)(qrow + s*16);
            qb[s] = q * sc;
        }
    }

    f32x16 y[2];
    #pragma unroll
    for (int i = 0; i < 16; ++i) { y[0][i] = 0.f; y[1][i] = 0.f; }

    const int lrow = t >> 2;
    const int loff = (t & 3) << 4;   // 16-key block per staging quarter
    {   // prologue: stage tile 0 into buffer 0 (V with nu swizzle)
        const uint4* gk = (const uint4*)(Qbase + (size_t)(keybase + lrow)*64 + loff);
        uint4 k0 = gk[0], k1 = gk[1];
        const uint4* gv = (const uint4*)(Vbase + (size_t)lrow*4096 + keybase + loff);
        uint4 v0 = gv[0], v1 = gv[1];
        *(uint4*)&Ksh[0][lrow][loff]     = k0;
        *(uint4*)&Ksh[0][lrow][loff + 8] = k1;
        uint4 pa = { v0.x, v0.y, v1.x, v1.y };   // slots 0-7 = keys 0-3,8-11
        uint4 pb = { v0.z, v0.w, v1.z, v1.w };   // slots 8-15 = keys 4-7,12-15
        *(uint4*)&Vts[0][lrow][loff]     = pa;
        *(uint4*)&Vts[0][lrow][loff + 8] = pb;
    }
    __syncthreads();

    for (int kb = 0; kb < niter; ++kb) {
        const int cur = kb & 1, nxt = cur ^ 1;

        // prefetch next tile into registers (in flight across compute phase)
        uint4 nk0 = {0,0,0,0}, nk1 = {0,0,0,0}, nv0 = {0,0,0,0}, nv1 = {0,0,0,0};
        if (kb < niter - 1) {
            const int keyn = keybase + (kb + 1)*64;
            const uint4* gk = (const uint4*)(Qbase + (size_t)(keyn + lrow)*64 + loff);
            nk0 = gk[0]; nk1 = gk[1];
            const uint4* gv = (const uint4*)(Vbase + (size_t)lrow*4096 + keyn + loff);
            nv0 = gv[0]; nv1 = gv[1];
        }

        // T = K·Qs^T : tt[u] covers keys u*32..+32 (scale pre-folded)
        f32x16 tt[2];
        #pragma unroll
        for (int i = 0; i < 16; ++i) { tt[0][i] = 0.f; tt[1][i] = 0.f; }
        #pragma unroll
        for (int s = 0; s < 4; ++s) {
            const int co = s*16 + hi*8;
            f16x8 ka0 = *(const f16x8*)&Ksh[cur][l32][co];
            f16x8 ka1 = *(const f16x8*)&Ksh[cur][32 + l32][co];
            tt[0] = __builtin_amdgcn_mfma_f32_32x32x16_f16(ka0, qb[s], tt[0], 0,0,0);
            tt[1] = __builtin_amdgcn_mfma_f32_32x32x16_f16(ka1, qb[s], tt[1], 0,0,0);
        }

        // sigmoid (pairwise rcp, t clamped) -> pack -> DIRECT A-frag
        #pragma unroll
        for (int u = 0; u < 2; ++u) {
            unsigned pk_[8];
            #pragma unroll
            for (int pr = 0; pr < 8; ++pr) {
                float t0 = __builtin_fminf(tt[u][2*pr+0], 60.0f);
                float t1 = __builtin_fminf(tt[u][2*pr+1], 60.0f);
                float e0 = __builtin_exp2f(t0);
                float e1 = __builtin_exp2f(t1);
                float d0 = 1.0f + e0, d1 = 1.0f + e1;
                float rr = __builtin_amdgcn_rcpf(d0 * d1);
                pk_[pr] = pkrtz(rr * d1, rr * d0);
            }
            #pragma unroll
            for (int sp = 0; sp < 2; ++sp) {
                union { unsigned u4[4]; f16x8 v; } sa;
                sa.u4[0] = pk_[sp*4 + 0];
                sa.u4[1] = pk_[sp*4 + 1];
                sa.u4[2] = pk_[sp*4 + 2];
                sa.u4[3] = pk_[sp*4 + 3];
                const int ks = u*2 + sp;
                const int co = ks*16 + hi*8;
                f16x8 vb0 = *(const f16x8*)&Vts[cur][l32][co];
                f16x8 vb1 = *(const f16x8*)&Vts[cur][32 + l32][co];
                y[0] = __builtin_amdgcn_mfma_f32_32x32x16_f16(sa.v, vb0, y[0], 0,0,0);
                y[1] = __builtin_amdgcn_mfma_f32_32x32x16_f16(sa.v, vb1, y[1], 0,0,0);
            }
        }

        // drain prefetch into the idle buffer (nobody reads nxt this iter)
        if (kb < niter - 1) {
            *(uint4*)&Ksh[nxt][lrow][loff]     = nk0;
            *(uint4*)&Ksh[nxt][lrow][loff + 8] = nk1;
            uint4 pa = { nv0.x, nv0.y, nv1.x, nv1.y };
            uint4 pb = { nv0.z, nv0.w, nv1.z, nv1.w };
            *(uint4*)&Vts[nxt][lrow][loff]     = pa;
            *(uint4*)&Vts[nxt][lrow][loff + 8] = pb;
        }
        __syncthreads();   // single barrier per iteration
    }

    // epilogue: P[ksplit][b][d][token]; token = mb*128 + w*32 + 8g + 4hi + e
    float* Pp = P + (((size_t)(ksplit*4 + b)) << 18);
    const int token0 = mb*128 + w*32 + hi*4;
    #pragma unroll
    for (int dt = 0; dt < 2; ++dt) {
        const int d = dt*32 + l32;
        #pragma unroll
        for (int g = 0; g < 4; ++g) {
            float4 v;
            v.x = y[dt][4*g+0]; v.y = y[dt][4*g+1];
            v.z = y[dt][4*g+2]; v.w = y[dt][4*g+3];
            *(float4*)&Pp[(size_t)d*4096 + token0 + 8*g] = v;
        }
    }
}

// ---------------------------------------------------------------------------
// final: out = p * (feature + x1 + g*sum_ks P_w[ks][b][d=w][token=h*64+c])
// ---------------------------------------------------------------------------
__global__ __launch_bounds__(256) void final_kernel(
    const float* __restrict__ feature, const float* __restrict__ x1,
    const float* __restrict__ Pin, const float* __restrict__ predict,
    const float* __restrict__ conv_w, const float* __restrict__ conv_b,
    const float* __restrict__ gate, float* __restrict__ out, int nsplit)
{
    const int i4 = blockIdx.x * 256 + threadIdx.x;   // [0, 262144)
    const int j = i4 << 2;
    const int pix = j >> 6;
    const float* row = predict + (size_t)pix * 19;
    float pv = conv_b[0];
    #pragma unroll
    for (int i = 0; i < 19; ++i) {
        float sg = __builtin_amdgcn_rcpf(1.0f + __builtin_exp2f(-1.442695041f * row[i]));
        pv += (1.0f - sg) * conv_w[i];
    }

    const int b = j >> 18, h = (j >> 12) & 63, d = (j >> 6) & 63, c = j & 63;
    const size_t pif = ((size_t)(b*64 + d) << 12) + h*64 + c;
    float sx = 0.f, sy = 0.f, sz = 0.f, sw = 0.f;
    for (int ks = 0; ks < nsplit; ++ks) {
        float4 pk = *(const float4*)&Pin[((size_t)ks << 20) + pif];
        sx += pk.x; sy += pk.y; sz += pk.z; sw += pk.w;
    }
    const float g = gate[0];
    float4 f = ((const float4*)feature)[i4];
    float4 x = ((const float4*)x1)[i4];
    float4 o;
    o.x = pv * (f.x + x.x + g * sx);
    o.y = pv * (f.y + x.y + g * sy);
    o.z = pv * (f.z + x.z + g * sz);
    o.w = pv * (f.w + x.w + g * sw);
    ((float4*)out)[i4] = o;
}

extern "C" void kernel_launch(void* const* d_in, const int* in_sizes, int n_in,
                              void* d_out, int out_size, void* d_ws, size_t ws_size,
                              hipStream_t stream) {
    const float* feature = (const float*)d_in[0];
    const float* predict = (const float*)d_in[1];
    const float* hq_w = (const float*)d_in[2];
    const float* hq_b = (const float*)d_in[3];
    const float* hv_w = (const float*)d_in[4];
    const float* hv_b = (const float*)d_in[5];
    const float* wq_w = (const float*)d_in[6];
    const float* wq_b = (const float*)d_in[7];
    const float* wv_w = (const float*)d_in[8];
    const float* wv_b = (const float*)d_in[9];
    const float* h_gate = (const float*)d_in[10];
    const float* w_gate = (const float*)d_in[11];
    const float* conv_w = (const float*)d_in[12];
    const float* conv_b = (const float*)d_in[13];
    float* out = (float*)d_out;

    // workspace: Qg 2MB | Vtg 2MB | x1 4MB | P nsplit*4MB (nsplit=4 -> 24 MiB)
    char* ws = (char*)d_ws;
    unsigned short* Qg  = (unsigned short*)(ws);
    unsigned short* Vtg = (unsigned short*)(ws + (2u << 20));
    float*          x1  = (float*)(ws + (4u << 20));
    float*          P   = (float*)(ws + (8u << 20));
    const int nsplit = 4;

    dim3 blk(256);
    // height stage
    prep_kernel<<<dim3(64, 4), blk, 0, stream>>>(feature, hq_w, hq_b, hv_w, hv_b,
                                                 Qg, Vtg);
    attn_kernel<<<dim3(32, 4, nsplit), blk, 0, stream>>>(Qg, Vtg, P);
    // width stage: x1 = feature + h_gate*sum(P) fused into staging
    prep_w_kernel<<<dim3(64, 4), blk, 0, stream>>>(feature, P, h_gate,
                                                   wq_w, wq_b, wv_w, wv_b,
                                                   Qg, Vtg, x1, nsplit);
    attn_kernel<<<dim3(32, 4, nsplit), blk, 0, stream>>>(Qg, Vtg, P);
    // out = p * (feature + x1 + w_gate*sum(P))
    final_kernel<<<dim3(1024), blk, 0, stream>>>(feature, x1, P, predict,
                                                 conv_w, conv_b, w_gate, out, nsplit);
}

// Round 12
// 175.736 us; speedup vs baseline: 1.6402x; 1.0235x over previous
//
#include <hip/hip_runtime.h>

// MFMA fragment types (f16)
typedef _Float16 f16x8 __attribute__((ext_vector_type(8)));
typedef __fp16   fp16x2 __attribute__((ext_vector_type(2)));
typedef float f32x16 __attribute__((ext_vector_type(16)));

__device__ __forceinline__ unsigned pkrtz(float a, float b) {
    fp16x2 h = __builtin_amdgcn_cvt_pkrtz(a, b);   // src0->low, src1->high
    union { fp16x2 h; unsigned u; } c; c.h = h; return c.u;
}

__device__ __forceinline__ unsigned short f2h(float f) {
    _Float16 h = (_Float16)f;
    union { _Float16 h; unsigned short s; } c; c.h = h; return c.s;
}

__device__ __forceinline__ f16x8 pack8(const float* v) {
    union { unsigned u[4]; f16x8 h; } c;
    c.u[0] = pkrtz(v[0], v[1]);
    c.u[1] = pkrtz(v[2], v[3]);
    c.u[2] = pkrtz(v[4], v[5]);
    c.u[3] = pkrtz(v[6], v[7]);
    return c.h;
}

// ---------------------------------------------------------------------------
// prep v2 (MFMA GEMM, r8-proven). 4 waves x one 32x32 tile each for BOTH
// Q and V; acc written through LDS (reusing weight buffers), then the
// r0-proven coalesced epilogue.
// ---------------------------------------------------------------------------
__global__ __launch_bounds__(256) void prep_kernel(
    const float* __restrict__ src,
    const float* __restrict__ wq, const float* __restrict__ bq,
    const float* __restrict__ wv, const float* __restrict__ bv,
    unsigned short* __restrict__ Qg, unsigned short* __restrict__ Vtg)
{
    __shared__ float slab[64][65];
    __shared__ float wqs[4160];   // weights [k*64+j]; reused as outQ[c*65+j]
    __shared__ float wvs[4160];   // weights [k*64+j]; reused as outV[c*65+j]

    const int t  = threadIdx.x;
    const int bx = blockIdx.x, b = blockIdx.y;
    const int lane = t & 63, w = t >> 6;
    const int l32 = lane & 31, hi = lane >> 5;

    {   // stage weights (linear [k*64+j])
        const float4* wq4 = (const float4*)wq;
        const float4* wv4 = (const float4*)wv;
        float4* q4 = (float4*)wqs; float4* v4 = (float4*)wvs;
        #pragma unroll
        for (int i = 0; i < 4; ++i) {
            q4[i*256 + t] = wq4[i*256 + t];
            v4[i*256 + t] = wv4[i*256 + t];
        }
    }
    {   // stage slab: k=h rows (stride 4096), bx=w fixed
        const int k = t >> 2, c0 = (t & 3) << 4;
        const size_t sb = (size_t)b*262144 + (size_t)k*4096 + (size_t)bx*64 + c0;
        #pragma unroll
        for (int i = 0; i < 4; ++i)
            *(float4*)&slab[k][c0 + i*4] = *(const float4*)&src[sb + i*4];
    }
    __syncthreads();

    const int mt = w >> 1, nt = w & 1;   // wave's 32x32 tile
    f16x8 xa[4], wqb[4], wvb[4];
    #pragma unroll
    for (int s = 0; s < 4; ++s) {
        const int k0 = s*16 + hi*8;
        float av[8], qv[8], vv[8];
        #pragma unroll
        for (int jj = 0; jj < 8; ++jj) {
            av[jj] = slab[k0 + jj][mt*32 + l32];
            qv[jj] = wqs[(k0 + jj)*64 + nt*32 + l32];
            vv[jj] = wvs[(k0 + jj)*64 + nt*32 + l32];
        }
        xa[s]  = pack8(av);
        wqb[s] = pack8(qv);
        wvb[s] = pack8(vv);
    }

    f32x16 fz;
    #pragma unroll
    for (int i = 0; i < 16; ++i) fz[i] = 0.f;
    f32x16 accQ = __builtin_amdgcn_mfma_f32_32x32x16_f16(xa[0], wqb[0], fz, 0,0,0);
    f32x16 accV = __builtin_amdgcn_mfma_f32_32x32x16_f16(xa[0], wvb[0], fz, 0,0,0);
    #pragma unroll
    for (int s = 1; s < 4; ++s) {
        accQ = __builtin_amdgcn_mfma_f32_32x32x16_f16(xa[s], wqb[s], accQ, 0,0,0);
        accV = __builtin_amdgcn_mfma_f32_32x32x16_f16(xa[s], wvb[s], accV, 0,0,0);
    }

    __syncthreads();   // all frag reads done -> safe to overwrite weight LDS

    {
        #pragma unroll
        for (int r = 0; r < 16; ++r) {
            const int crow = mt*32 + (r&3) + 8*(r>>2) + 4*hi;
            wqs[crow*65 + nt*32 + l32] = accQ[r];
            wvs[crow*65 + nt*32 + l32] = accV[r];
        }
    }
    __syncthreads();

    const int c = t & 63, jg = t >> 6;
    float qa[16], va[16];
    #pragma unroll
    for (int jj = 0; jj < 16; ++jj) {
        qa[jj] = bq[jg*16+jj] + wqs[c*65 + jg*16 + jj];
        va[jj] = bv[jg*16+jj] + wvs[c*65 + jg*16 + jj];
    }
    const int token = bx*64 + c;
    union { unsigned u[8]; uint4 v[2]; } qp;
    #pragma unroll
    for (int jj = 0; jj < 8; ++jj) qp.u[jj] = pkrtz(qa[2*jj], qa[2*jj+1]);
    const size_t qoff = ((size_t)b*4096 + token)*64 + jg*16;
    *(uint4*)&Qg[qoff]     = qp.v[0];
    *(uint4*)&Qg[qoff + 8] = qp.v[1];
    #pragma unroll
    for (int jj = 0; jj < 16; ++jj)
        Vtg[((size_t)b*64 + jg*16 + jj)*4096 + token] = f2h(va[jj]);
}

// ---------------------------------------------------------------------------
// prep_w v2 (same MFMA GEMM) FUSED with fold_h (r8-proven).
// ---------------------------------------------------------------------------
__global__ __launch_bounds__(256) void prep_w_kernel(
    const float* __restrict__ feature, const float* __restrict__ Pin,
    const float* __restrict__ gate,
    const float* __restrict__ wq, const float* __restrict__ bq,
    const float* __restrict__ wv, const float* __restrict__ bv,
    unsigned short* __restrict__ Qg, unsigned short* __restrict__ Vtg,
    float* __restrict__ x1out, int nsplit)
{
    __shared__ float slab[64][65];
    __shared__ float wqs[4160];
    __shared__ float wvs[4160];

    const int t  = threadIdx.x;
    const int bx = blockIdx.x, b = blockIdx.y;   // bx = h
    const int lane = t & 63, w = t >> 6;
    const int l32 = lane & 31, hi = lane >> 5;

    {   // stage weights
        const float4* wq4 = (const float4*)wq;
        const float4* wv4 = (const float4*)wv;
        float4* q4 = (float4*)wqs; float4* v4 = (float4*)wvs;
        #pragma unroll
        for (int i = 0; i < 4; ++i) {
            q4[i*256 + t] = wq4[i*256 + t];
            v4[i*256 + t] = wv4[i*256 + t];
        }
    }
    {   // stage slab with inline fold: P_h[ks][b][d=h][token=w*64+c]
        const int k = t >> 2, c0 = (t & 3) << 4;
        const size_t off = (size_t)bx*4096 + (size_t)k*64 + c0;  // h*4096 + w*64 + c
        const size_t fb  = (size_t)b*262144 + off;
        const float g = gate[0];
        #pragma unroll
        for (int i = 0; i < 4; ++i) {
            float4 v  = *(const float4*)&feature[fb + i*4];
            float sx = 0.f, sy = 0.f, sz = 0.f, sw = 0.f;
            for (int ks = 0; ks < nsplit; ++ks) {
                float4 pk = *(const float4*)&Pin[((size_t)(ks*4 + b) << 18) + off + i*4];
                sx += pk.x; sy += pk.y; sz += pk.z; sw += pk.w;
            }
            v.x += g * sx; v.y += g * sy; v.z += g * sz; v.w += g * sw;
            *(float4*)&slab[k][c0 + i*4] = v;
            *(float4*)&x1out[fb + i*4] = v;
        }
    }
    __syncthreads();

    const int mt = w >> 1, nt = w & 1;
    f16x8 xa[4], wqb[4], wvb[4];
    #pragma unroll
    for (int s = 0; s < 4; ++s) {
        const int k0 = s*16 + hi*8;
        float av[8], qv[8], vv[8];
        #pragma unroll
        for (int jj = 0; jj < 8; ++jj) {
            av[jj] = slab[k0 + jj][mt*32 + l32];
            qv[jj] = wqs[(k0 + jj)*64 + nt*32 + l32];
            vv[jj] = wvs[(k0 + jj)*64 + nt*32 + l32];
        }
        xa[s]  = pack8(av);
        wqb[s] = pack8(qv);
        wvb[s] = pack8(vv);
    }

    f32x16 fz;
    #pragma unroll
    for (int i = 0; i < 16; ++i) fz[i] = 0.f;
    f32x16 accQ = __builtin_amdgcn_mfma_f32_32x32x16_f16(xa[0], wqb[0], fz, 0,0,0);
    f32x16 accV = __builtin_amdgcn_mfma_f32_32x32x16_f16(xa[0], wvb[0], fz, 0,0,0);
    #pragma unroll
    for (int s = 1; s < 4; ++s) {
        accQ = __builtin_amdgcn_mfma_f32_32x32x16_f16(xa[s], wqb[s], accQ, 0,0,0);
        accV = __builtin_amdgcn_mfma_f32_32x32x16_f16(xa[s], wvb[s], accV, 0,0,0);
    }

    __syncthreads();

    {
        #pragma unroll
        for (int r = 0; r < 16; ++r) {
            const int crow = mt*32 + (r&3) + 8*(r>>2) + 4*hi;
            wqs[crow*65 + nt*32 + l32] = accQ[r];
            wvs[crow*65 + nt*32 + l32] = accV[r];
        }
    }
    __syncthreads();

    const int c = t & 63, jg = t >> 6;
    float qa[16], va[16];
    #pragma unroll
    for (int jj = 0; jj < 16; ++jj) {
        qa[jj] = bq[jg*16+jj] + wqs[c*65 + jg*16 + jj];
        va[jj] = bv[jg*16+jj] + wvs[c*65 + jg*16 + jj];
    }
    const int token = bx*64 + c;
    union { unsigned u[8]; uint4 v[2]; } qp;
    #pragma unroll
    for (int jj = 0; jj < 8; ++jj) qp.u[jj] = pkrtz(qa[2*jj], qa[2*jj+1]);
    const size_t qoff = ((size_t)b*4096 + token)*64 + jg*16;
    *(uint4*)&Qg[qoff]     = qp.v[0];
    *(uint4*)&Qg[qoff + 8] = qp.v[1];
    #pragma unroll
    for (int jj = 0; jj < 16; ++jj)
        Vtg[((size_t)b*64 + jg*16 + jj)*4096 + token] = f2h(va[jj]);
}

// ---------------------------------------------------------------------------
// attn v21 = r0 structure + **depth-2 register prefetch** (T4 port).
// Theory: after each barrier all 8 waves/CU burst-issue their prefetch
// loads; under that burst L2 latency exceeds the ~700cyc same-iter compute,
// so each iter stalls at the vmcnt before the ds_write and the barrier
// propagates the slowest wave (m233's 2-phase stall). Depth-2: tile k+2's
// loads are issued at iter k, ds_written at iter k+1 -> ~1.5 phases of
// cover instead of ~0.7. Two NAMED regsets A/B (static indexing, rule #20),
// even/odd phases explicit, niter hardcoded 16 (nsplit=4).
// Everything else identical to the r0/r11 attn (best measured 44.8us).
// ---------------------------------------------------------------------------
__global__ __launch_bounds__(256) void attn_kernel(
    const unsigned short* __restrict__ Qg,
    const unsigned short* __restrict__ Vtg,
    float* __restrict__ P)
{
    __shared__ unsigned short Ksh[2][64][72];
    __shared__ unsigned short Vts[2][64][72];

    const int t = threadIdx.x;
    const int mb = blockIdx.x, b = blockIdx.y, ksplit = blockIdx.z;
    const int keybase = ksplit * 1024;            // nsp = 4
    const int lane = t & 63, w = t >> 6;
    const int l32 = lane & 31, hi = lane >> 5;

    const unsigned short* Qbase = Qg  + (size_t)b*262144;
    const unsigned short* Vbase = Vtg + (size_t)b*262144;

    // Q B-frags (n=query=l32, k=d=s*16+hi*8+j), scaled by -0.125*log2(e)
    f16x8 qb[4];
    {
        const unsigned short* qrow = Qbase + (size_t)(mb*128 + w*32 + l32)*64 + hi*8;
        const _Float16 sc = (_Float16)(-0.180336880f);
        #pragma unroll
        for (int s = 0; s < 4; ++s) {
            f16x8 q = *(const f16x8*)(qrow + s*16);
            qb[s] = q * sc;
        }
    }

    f32x16 y[2];
    #pragma unroll
    for (int i = 0; i < 16; ++i) { y[0][i] = 0.f; y[1][i] = 0.f; }

    const int lrow = t >> 2;
    const int loff = (t & 3) << 4;   // 16-key block per staging quarter

    // regset A holds even tiles (0,2,..), regset B odd tiles (1,3,..)
    uint4 ak0, ak1, av0, av1;
    uint4 bk0, bk1, bv0, bv1;

    #define LOADT(K0_, K1_, V0_, V1_, TILE_)  do {                                 \
        const int keyn_ = keybase + (TILE_)*64;                                    \
        const uint4* gk_ = (const uint4*)(Qbase + (size_t)(keyn_ + lrow)*64 + loff); \
        K0_ = gk_[0]; K1_ = gk_[1];                                                \
        const uint4* gv_ = (const uint4*)(Vbase + (size_t)lrow*4096 + keyn_ + loff); \
        V0_ = gv_[0]; V1_ = gv_[1];                                                \
    } while (0)

    #define WRITET(K0_, K1_, V0_, V1_, BUF_)  do {                                 \
        *(uint4*)&Ksh[BUF_][lrow][loff]     = K0_;                                 \
        *(uint4*)&Ksh[BUF_][lrow][loff + 8] = K1_;                                 \
        uint4 pa_ = { V0_.x, V0_.y, V1_.x, V1_.y };                                \
        uint4 pb_ = { V0_.z, V0_.w, V1_.z, V1_.w };                                \
        *(uint4*)&Vts[BUF_][lrow][loff]     = pa_;                                 \
        *(uint4*)&Vts[BUF_][lrow][loff + 8] = pb_;                                 \
    } while (0)

    // prologue: T0 -> A -> buf0 ; T1 -> B (in flight across barrier)
    LOADT(ak0, ak1, av0, av1, 0);
    WRITET(ak0, ak1, av0, av1, 0);
    LOADT(bk0, bk1, bv0, bv1, 1);
    __syncthreads();

    #define COMPUTE(CUR_)  do {                                                    \
        f32x16 tt[2];                                                              \
        _Pragma("unroll")                                                          \
        for (int i = 0; i < 16; ++i) { tt[0][i] = 0.f; tt[1][i] = 0.f; }           \
        _Pragma("unroll")                                                          \
        for (int s = 0; s < 4; ++s) {                                              \
            const int co = s*16 + hi*8;                                            \
            f16x8 ka0 = *(const f16x8*)&Ksh[CUR_][l32][co];                        \
            f16x8 ka1 = *(const f16x8*)&Ksh[CUR_][32 + l32][co];                   \
            tt[0] = __builtin_amdgcn_mfma_f32_32x32x16_f16(ka0, qb[s], tt[0], 0,0,0); \
            tt[1] = __builtin_amdgcn_mfma_f32_32x32x16_f16(ka1, qb[s], tt[1], 0,0,0); \
        }                                                                          \
        _Pragma("unroll")                                                          \
        for (int u = 0; u < 2; ++u) {                                              \
            unsigned pk_[8];                                                       \
            _Pragma("unroll")                                                      \
            for (int pr = 0; pr < 8; ++pr) {                                       \
                float t0 = __builtin_fminf(tt[u][2*pr+0], 60.0f);                  \
                float t1 = __builtin_fminf(tt[u][2*pr+1], 60.0f);                  \
                float e0 = __builtin_exp2f(t0);                                    \
                float e1 = __builtin_exp2f(t1);                                    \
                float d0 = 1.0f + e0, d1 = 1.0f + e1;                              \
                float rr = __builtin_amdgcn_rcpf(d0 * d1);                         \
                pk_[pr] = pkrtz(rr * d1, rr * d0);                                 \
            }                                                                      \
            _Pragma("unroll")                                                      \
            for (int sp = 0; sp < 2; ++sp) {                                       \
                union { unsigned u4[4]; f16x8 v; } sa;                             \
                sa.u4[0] = pk_[sp*4 + 0];                                          \
                sa.u4[1] = pk_[sp*4 + 1];                                          \
                sa.u4[2] = pk_[sp*4 + 2];                                          \
                sa.u4[3] = pk_[sp*4 + 3];                                          \
                const int ks = u*2 + sp;                                           \
                const int co = ks*16 + hi*8;                                       \
                f16x8 vb0 = *(const f16x8*)&Vts[CUR_][l32][co];                    \
                f16x8 vb1 = *(const f16x8*)&Vts[CUR_][32 + l32][co];               \
                y[0] = __builtin_amdgcn_mfma_f32_32x32x16_f16(sa.v, vb0, y[0], 0,0,0); \
                y[1] = __builtin_amdgcn_mfma_f32_32x32x16_f16(sa.v, vb1, y[1], 0,0,0); \
            }                                                                      \
        }                                                                          \
    } while (0)

    // 8 even/odd phase pairs (tiles 0..15)
    #pragma unroll
    for (int it = 0; it < 8; ++it) {
        const int kb0 = 2*it;        // even tile, data in buf0
        // EVEN phase: issue loads for tile kb0+2 into A (A's data is in LDS)
        if (kb0 + 2 < 16) LOADT(ak0, ak1, av0, av1, kb0 + 2);
        COMPUTE(0);
        // write tile kb0+1 from B into buf1 (B loaded 1.5 phases ago)
        WRITET(bk0, bk1, bv0, bv1, 1);
        __syncthreads();

        const int kb1 = kb0 + 1;     // odd tile, data in buf1
        // ODD phase: issue loads for tile kb1+2 into B
        if (kb1 + 2 < 16) LOADT(bk0, bk1, bv0, bv1, kb1 + 2);
        COMPUTE(1);
        // write tile kb1+1 from A into buf0 (skip after last tile)
        if (kb1 < 15) {
            WRITET(ak0, ak1, av0, av1, 0);
            __syncthreads();
        }
    }

    #undef LOADT
    #undef WRITET
    #undef COMPUTE

    // epilogue: P[ksplit][b][d][token]; token = mb*128 + w*32 + 8g + 4hi + e
    float* Pp = P + (((size_t)(ksplit*4 + b)) << 18);
    const int token0 = mb*128 + w*32 + hi*4;
    #pragma unroll
    for (int dt = 0; dt < 2; ++dt) {
        const int d = dt*32 + l32;
        #pragma unroll
        for (int g = 0; g < 4; ++g) {
            float4 v;
            v.x = y[dt][4*g+0]; v.y = y[dt][4*g+1];
            v.z = y[dt][4*g+2]; v.w = y[dt][4*g+3];
            *(float4*)&Pp[(size_t)d*4096 + token0 + 8*g] = v;
        }
    }
}

// ---------------------------------------------------------------------------
// final: out = p * (feature + x1 + g*sum_ks P_w[ks][b][d=w][token=h*64+c])
// ---------------------------------------------------------------------------
__global__ __launch_bounds__(256) void final_kernel(
    const float* __restrict__ feature, const float* __restrict__ x1,
    const float* __restrict__ Pin, const float* __restrict__ predict,
    const float* __restrict__ conv_w, const float* __restrict__ conv_b,
    const float* __restrict__ gate, float* __restrict__ out, int nsplit)
{
    const int i4 = blockIdx.x * 256 + threadIdx.x;   // [0, 262144)
    const int j = i4 << 2;
    const int pix = j >> 6;
    const float* row = predict + (size_t)pix * 19;
    float pv = conv_b[0];
    #pragma unroll
    for (int i = 0; i < 19; ++i) {
        float sg = __builtin_amdgcn_rcpf(1.0f + __builtin_exp2f(-1.442695041f * row[i]));
        pv += (1.0f - sg) * conv_w[i];
    }

    const int b = j >> 18, h = (j >> 12) & 63, d = (j >> 6) & 63, c = j & 63;
    const size_t pif = ((size_t)(b*64 + d) << 12) + h*64 + c;
    float sx = 0.f, sy = 0.f, sz = 0.f, sw = 0.f;
    for (int ks = 0; ks < nsplit; ++ks) {
        float4 pk = *(const float4*)&Pin[((size_t)ks << 20) + pif];
        sx += pk.x; sy += pk.y; sz += pk.z; sw += pk.w;
    }
    const float g = gate[0];
    float4 f = ((const float4*)feature)[i4];
    float4 x = ((const float4*)x1)[i4];
    float4 o;
    o.x = pv * (f.x + x.x + g * sx);
    o.y = pv * (f.y + x.y + g * sy);
    o.z = pv * (f.z + x.z + g * sz);
    o.w = pv * (f.w + x.w + g * sw);
    ((float4*)out)[i4] = o;
}

extern "C" void kernel_launch(void* const* d_in, const int* in_sizes, int n_in,
                              void* d_out, int out_size, void* d_ws, size_t ws_size,
                              hipStream_t stream) {
    const float* feature = (const float*)d_in[0];
    const float* predict = (const float*)d_in[1];
    const float* hq_w = (const float*)d_in[2];
    const float* hq_b = (const float*)d_in[3];
    const float* hv_w = (const float*)d_in[4];
    const float* hv_b = (const float*)d_in[5];
    const float* wq_w = (const float*)d_in[6];
    const float* wq_b = (const float*)d_in[7];
    const float* wv_w = (const float*)d_in[8];
    const float* wv_b = (const float*)d_in[9];
    const float* h_gate = (const float*)d_in[10];
    const float* w_gate = (const float*)d_in[11];
    const float* conv_w = (const float*)d_in[12];
    const float* conv_b = (const float*)d_in[13];
    float* out = (float*)d_out;

    // workspace: Qg 2MB | Vtg 2MB | x1 4MB | P nsplit*4MB (nsplit=4 -> 24 MiB)
    char* ws = (char*)d_ws;
    unsigned short* Qg  = (unsigned short*)(ws);
    unsigned short* Vtg = (unsigned short*)(ws + (2u << 20));
    float*          x1  = (float*)(ws + (4u << 20));
    float*          P   = (float*)(ws + (8u << 20));
    const int nsplit = 4;

    dim3 blk(256);
    // height stage
    prep_kernel<<<dim3(64, 4), blk, 0, stream>>>(feature, hq_w, hq_b, hv_w, hv_b,
                                                 Qg, Vtg);
    attn_kernel<<<dim3(32, 4, nsplit), blk, 0, stream>>>(Qg, Vtg, P);
    // width stage: x1 = feature + h_gate*sum(P) fused into staging
    prep_w_kernel<<<dim3(64, 4), blk, 0, stream>>>(feature, P, h_gate,
                                                   wq_w, wq_b, wv_w, wv_b,
                                                   Qg, Vtg, x1, nsplit);
    attn_kernel<<<dim3(32, 4, nsplit), blk, 0, stream>>>(Qg, Vtg, P);
    // out = p * (feature + x1 + w_gate*sum(P))
    final_kernel<<<dim3(1024), blk, 0, stream>>>(feature, x1, P, predict,
                                                 conv_w, conv_b, w_gate, out, nsplit);
}